// Round 6
// baseline (7281.077 us; speedup 1.0000x reference)
//
#include <hip/hip_runtime.h>
#include <cmath>

namespace {

constexpr int Tn = 64;
constexpr int Bn = 512;
constexpr int Xn = 784;
constexpr int XnP = 800;
constexpr int Fn = 64;
constexpr int Zn = 64;
constexpr int Hn = 512;

typedef unsigned short us;
typedef __attribute__((ext_vector_type(8))) short bf16x8;
typedef __attribute__((ext_vector_type(4))) float f32x4;

__device__ __forceinline__ us f2b(float v) {
  unsigned int u = __float_as_uint(v);
  return (us)((u + 0x7FFFu + ((u >> 16) & 1u)) >> 16);
}
__device__ __forceinline__ float b2f(us u) { return __uint_as_float(((unsigned int)u) << 16); }
__device__ __forceinline__ float sigmf(float v) { return 1.0f / (1.0f + __expf(-v)); }
__device__ __forceinline__ float splusf(float v) {
  return v > 0.0f ? (v + log1pf(__expf(-v))) : log1pf(__expf(v));
}
__device__ __forceinline__ float block_sum(float v, float* red) {
  #pragma unroll
  for (int off = 32; off > 0; off >>= 1) v += __shfl_down(v, off, 64);
  if ((threadIdx.x & 63) == 0) red[threadIdx.x >> 6] = v;
  __syncthreads();
  float s = 0.0f;
  if (threadIdx.x == 0) s = red[0] + red[1] + red[2] + red[3];
  return s;
}

// ---- converters (weights only) ----
__global__ void cvt(const float* __restrict__ s, us* __restrict__ d, int n) {
  int i = blockIdx.x * 256 + threadIdx.x;
  if (i < n) d[i] = f2b(s[i]);
}
__global__ void cvt_pad(const float* __restrict__ s, us* __restrict__ d, int C, int Cp, int n) {
  int i = blockIdx.x * 256 + threadIdx.x;
  if (i < n) {
    int r = i / Cp, c = i - r * Cp;
    d[i] = (c < C) ? f2b(s[(size_t)r * C + c]) : (us)0;
  }
}

// ================= double-buffered tile device functions =================
// 64x64 GEMM tile: C = act(sum_seg A.W^T [+initC] [+bias]). smem >= 20480 B.
template <int NSEG, bool RELU, bool F32OUT, bool HASINIT, bool HASBIAS>
__device__ void tile_gemmx(
    int bx, int by,
    const us* A0, const us* W0, int ldw0, int K0,
    const us* A1, const us* W1, int ldw1, int K1,
    const float* initC, int ldi, const float* bias,
    void* Cout, int ldc, char* smemc)
{
  const int tid = threadIdx.x, srow = tid >> 2, scb = (tid & 3) * 8;
  const int lane = tid & 63, w = tid >> 6, l15 = lane & 15, q = lane >> 4;
  const int m0 = by * 64, n0 = bx * 64;
  f32x4 acc[4];
  if (HASINIT) {
    #pragma unroll
    for (int j = 0; j < 4; ++j)
      #pragma unroll
      for (int r = 0; r < 4; ++r)
        acc[j][r] = initC[(size_t)(m0 + w * 16 + q * 4 + r) * ldi + n0 + j * 16 + l15];
  } else {
    #pragma unroll
    for (int j = 0; j < 4; ++j) acc[j] = (f32x4){0.f, 0.f, 0.f, 0.f};
  }
  const int nt0 = K0 / 32;
  const int nt = (NSEG == 2) ? nt0 + K1 / 32 : nt0;
  auto ld = [&](int kt, uint4& av, uint4& wv) {
    if (NSEG == 2 && kt >= nt0) {
      const int k = (kt - nt0) * 32;
      av = *(const uint4*)(A1 + (size_t)(m0 + srow) * K1 + k + scb);
      wv = *(const uint4*)(W1 + (size_t)(n0 + srow) * ldw1 + k + scb);
    } else {
      const int k = kt * 32;
      av = *(const uint4*)(A0 + (size_t)(m0 + srow) * K0 + k + scb);
      wv = *(const uint4*)(W0 + (size_t)(n0 + srow) * ldw0 + k + scb);
    }
  };
  uint4 av, wv;
  ld(0, av, wv);
  *(uint4*)&((us*)smemc)[srow * 40 + scb] = av;
  *(uint4*)&((us*)(smemc + 5120))[srow * 40 + scb] = wv;
  __syncthreads();
  for (int kt = 0; kt < nt; ++kt) {
    const int cur = kt & 1;
    us* Asc = (us*)(smemc + cur * 10240);
    us* Bsc = (us*)(smemc + cur * 10240 + 5120);
    const bool more = (kt + 1 < nt);
    if (more) ld(kt + 1, av, wv);
    bf16x8 a = *(const bf16x8*)&Asc[(w * 16 + l15) * 40 + q * 8];
    #pragma unroll
    for (int j = 0; j < 4; ++j) {
      bf16x8 b = *(const bf16x8*)&Bsc[(j * 16 + l15) * 40 + q * 8];
      acc[j] = __builtin_amdgcn_mfma_f32_16x16x32_bf16(a, b, acc[j], 0, 0, 0);
    }
    if (more) {
      *(uint4*)&((us*)(smemc + (cur ^ 1) * 10240))[srow * 40 + scb] = av;
      *(uint4*)&((us*)(smemc + (cur ^ 1) * 10240 + 5120))[srow * 40 + scb] = wv;
    }
    __syncthreads();
  }
  #pragma unroll
  for (int j = 0; j < 4; ++j) {
    const int col = n0 + j * 16 + l15;
    const float bv = HASBIAS ? bias[col] : 0.f;
    #pragma unroll
    for (int r = 0; r < 4; ++r) {
      const int row = m0 + w * 16 + q * 4 + r;
      float v = acc[j][r] + bv;
      if (RELU) v = fmaxf(v, 0.f);
      if (F32OUT) ((float*)Cout)[(size_t)row * ldc + col] = v;
      else        ((us*)Cout)[(size_t)row * ldc + col] = f2b(v);
    }
  }
}

// Phase-A GEMM1: A read directly from fp32 x (cols clamped at 784), K=800.
__device__ void tile_gA1(int bx, int by, const float* __restrict__ X, const us* W,
                         const float* bias, us* C, char* smemc)
{
  const int tid = threadIdx.x, srow = tid >> 2, scb = (tid & 3) * 8;
  const int lane = tid & 63, w = tid >> 6, l15 = lane & 15, q = lane >> 4;
  const int m0 = by * 64, n0 = bx * 64;
  f32x4 acc[4];
  #pragma unroll
  for (int j = 0; j < 4; ++j) acc[j] = (f32x4){0.f, 0.f, 0.f, 0.f};
  auto ldA = [&](int k) -> uint4 {
    if (k + scb < Xn) {
      const float* p = X + (size_t)(m0 + srow) * Xn + k + scb;
      float4 f0 = *(const float4*)p;
      float4 f1 = *(const float4*)(p + 4);
      union { us h[8]; uint4 u; } pk;
      pk.h[0] = f2b(f0.x); pk.h[1] = f2b(f0.y); pk.h[2] = f2b(f0.z); pk.h[3] = f2b(f0.w);
      pk.h[4] = f2b(f1.x); pk.h[5] = f2b(f1.y); pk.h[6] = f2b(f1.z); pk.h[7] = f2b(f1.w);
      return pk.u;
    }
    return (uint4){0, 0, 0, 0};
  };
  const int nt = XnP / 32;  // 25
  uint4 av = ldA(0);
  uint4 wv = *(const uint4*)(W + (size_t)(n0 + srow) * XnP + scb);
  *(uint4*)&((us*)smemc)[srow * 40 + scb] = av;
  *(uint4*)&((us*)(smemc + 5120))[srow * 40 + scb] = wv;
  __syncthreads();
  for (int kt = 0; kt < nt; ++kt) {
    const int cur = kt & 1;
    us* Asc = (us*)(smemc + cur * 10240);
    us* Bsc = (us*)(smemc + cur * 10240 + 5120);
    const bool more = (kt + 1 < nt);
    if (more) {
      av = ldA((kt + 1) * 32);
      wv = *(const uint4*)(W + (size_t)(n0 + srow) * XnP + (kt + 1) * 32 + scb);
    }
    bf16x8 a = *(const bf16x8*)&Asc[(w * 16 + l15) * 40 + q * 8];
    #pragma unroll
    for (int j = 0; j < 4; ++j) {
      bf16x8 b = *(const bf16x8*)&Bsc[(j * 16 + l15) * 40 + q * 8];
      acc[j] = __builtin_amdgcn_mfma_f32_16x16x32_bf16(a, b, acc[j], 0, 0, 0);
    }
    if (more) {
      *(uint4*)&((us*)(smemc + (cur ^ 1) * 10240))[srow * 40 + scb] = av;
      *(uint4*)&((us*)(smemc + (cur ^ 1) * 10240 + 5120))[srow * 40 + scb] = wv;
    }
    __syncthreads();
  }
  #pragma unroll
  for (int j = 0; j < 4; ++j) {
    const int col = n0 + j * 16 + l15;
    const float bv = bias[col];
    #pragma unroll
    for (int r = 0; r < 4; ++r) {
      const int row = m0 + w * 16 + q * 4 + r;
      C[(size_t)row * Hn + col] = f2b(fmaxf(acc[j][r] + bv, 0.f));
    }
  }
}

// Phase-B GRU tile (gi = A0@Wih^T then gh = h@Whh^T; both ldw=512). smem >= 40960 B.
__device__ void tile_gru_fe(
    int bx, int by, const us* A0, const us* Wih,
    const us* hprev, const us* Whh,
    const float* bih, const float* bhh, us* hnew, char* smemc)
{
  const int tid = threadIdx.x, srow = tid >> 2, scb = (tid & 3) * 8;
  const int lane = tid & 63, w = tid >> 6, l15 = lane & 15, q = lane >> 4;
  const int m0 = by * 64, c0 = bx * 64;
  f32x4 aR[4], aZ[4], aI[4], aH[4];
  #pragma unroll
  for (int j = 0; j < 4; ++j) {
    aR[j] = (f32x4){0.f, 0.f, 0.f, 0.f}; aZ[j] = aR[j]; aI[j] = aR[j]; aH[j] = aR[j];
  }
  auto ld = [&](int kt, uint4& av, uint4& rv, uint4& zv, uint4& nv) {
    const bool hseg = kt >= 16;
    const us* A  = hseg ? hprev : A0;
    const us* Wb = hseg ? Whh : Wih;
    const int k = (kt & 15) * 32;
    av = *(const uint4*)(A + (size_t)(m0 + srow) * Hn + k + scb);
    const us* wr = Wb + (size_t)(c0 + srow) * Hn + k + scb;
    rv = *(const uint4*)wr;
    zv = *(const uint4*)(wr + 262144);
    nv = *(const uint4*)(wr + 524288);
  };
  uint4 av, rv, zv, nv;
  ld(0, av, rv, zv, nv);
  *(uint4*)&((us*)smemc)[srow * 40 + scb] = av;
  *(uint4*)&((us*)(smemc + 5120))[srow * 40 + scb] = rv;
  *(uint4*)&((us*)(smemc + 10240))[srow * 40 + scb] = zv;
  *(uint4*)&((us*)(smemc + 15360))[srow * 40 + scb] = nv;
  __syncthreads();
  for (int kt = 0; kt < 32; ++kt) {
    const int cur = kt & 1;
    char* base = smemc + cur * 20480;
    const bool hseg = kt >= 16;
    const bool more = (kt + 1 < 32);
    if (more) ld(kt + 1, av, rv, zv, nv);
    bf16x8 a = *(const bf16x8*)&((us*)base)[(w * 16 + l15) * 40 + q * 8];
    #pragma unroll
    for (int j = 0; j < 4; ++j) {
      bf16x8 br = *(const bf16x8*)&((us*)(base + 5120))[(j * 16 + l15) * 40 + q * 8];
      bf16x8 bz = *(const bf16x8*)&((us*)(base + 10240))[(j * 16 + l15) * 40 + q * 8];
      bf16x8 bn = *(const bf16x8*)&((us*)(base + 15360))[(j * 16 + l15) * 40 + q * 8];
      aR[j] = __builtin_amdgcn_mfma_f32_16x16x32_bf16(a, br, aR[j], 0, 0, 0);
      aZ[j] = __builtin_amdgcn_mfma_f32_16x16x32_bf16(a, bz, aZ[j], 0, 0, 0);
      if (hseg) aH[j] = __builtin_amdgcn_mfma_f32_16x16x32_bf16(a, bn, aH[j], 0, 0, 0);
      else      aI[j] = __builtin_amdgcn_mfma_f32_16x16x32_bf16(a, bn, aI[j], 0, 0, 0);
    }
    if (more) {
      char* nb = smemc + (cur ^ 1) * 20480;
      *(uint4*)&((us*)nb)[srow * 40 + scb] = av;
      *(uint4*)&((us*)(nb + 5120))[srow * 40 + scb] = rv;
      *(uint4*)&((us*)(nb + 10240))[srow * 40 + scb] = zv;
      *(uint4*)&((us*)(nb + 15360))[srow * 40 + scb] = nv;
    }
    __syncthreads();
  }
  #pragma unroll
  for (int j = 0; j < 4; ++j) {
    const int c = c0 + j * 16 + l15;
    const float bR = bih[c] + bhh[c];
    const float bZ = bih[Hn + c] + bhh[Hn + c];
    const float bI = bih[2 * Hn + c];
    const float bH = bhh[2 * Hn + c];
    #pragma unroll
    for (int r = 0; r < 4; ++r) {
      const int m = m0 + w * 16 + q * 4 + r;
      const float h = b2f(hprev[(size_t)m * Hn + c]);
      const float rg = sigmf(aR[j][r] + bR);
      const float zg = sigmf(aZ[j][r] + bZ);
      const float ng = tanhf(aI[j][r] + bI + rg * (aH[j][r] + bH));
      hnew[(size_t)m * Hn + c] = f2b((1.0f - zg) * ng + zg * h);
    }
  }
}

// Phase-D GRU final tile: phiz seg GEMM + fp32 preaccumulators. smem >= 40960 B.
__device__ void tile_gru_fin(
    int bx, int by, const us* phiz, const us* rWih,
    const float* gipre, const float* ghpre, const us* hprev,
    const float* bih, const float* bhh, us* hnew, char* smemc)
{
  const int tid = threadIdx.x, srow = tid >> 2, scb = (tid & 3) * 8;
  const int lane = tid & 63, w = tid >> 6, l15 = lane & 15, q = lane >> 4;
  const int m0 = by * 64, c0 = bx * 64;
  f32x4 aR[4], aZ[4], aI[4];
  float aH[4][4];
  #pragma unroll
  for (int j = 0; j < 4; ++j) {
    const int c = c0 + j * 16 + l15;
    #pragma unroll
    for (int r = 0; r < 4; ++r) {
      const size_t row = (size_t)(m0 + w * 16 + q * 4 + r) * 1536;
      aR[j][r] = gipre[row + c] + ghpre[row + c];
      aZ[j][r] = gipre[row + 512 + c] + ghpre[row + 512 + c];
      aI[j][r] = gipre[row + 1024 + c];
      aH[j][r] = ghpre[row + 1024 + c];
    }
  }
  auto ld = [&](int kt, uint4& av, uint4& rv, uint4& zv, uint4& nv) {
    const int k = kt * 32;
    av = *(const uint4*)(phiz + (size_t)(m0 + srow) * Hn + k + scb);
    const us* wr = rWih + (size_t)(c0 + srow) * 1536 + 512 + k + scb;
    rv = *(const uint4*)wr;
    zv = *(const uint4*)(wr + 786432);
    nv = *(const uint4*)(wr + 1572864);
  };
  uint4 av, rv, zv, nv;
  ld(0, av, rv, zv, nv);
  *(uint4*)&((us*)smemc)[srow * 40 + scb] = av;
  *(uint4*)&((us*)(smemc + 5120))[srow * 40 + scb] = rv;
  *(uint4*)&((us*)(smemc + 10240))[srow * 40 + scb] = zv;
  *(uint4*)&((us*)(smemc + 15360))[srow * 40 + scb] = nv;
  __syncthreads();
  for (int kt = 0; kt < 16; ++kt) {
    const int cur = kt & 1;
    char* base = smemc + cur * 20480;
    const bool more = (kt + 1 < 16);
    if (more) ld(kt + 1, av, rv, zv, nv);
    bf16x8 a = *(const bf16x8*)&((us*)base)[(w * 16 + l15) * 40 + q * 8];
    #pragma unroll
    for (int j = 0; j < 4; ++j) {
      bf16x8 br = *(const bf16x8*)&((us*)(base + 5120))[(j * 16 + l15) * 40 + q * 8];
      bf16x8 bz = *(const bf16x8*)&((us*)(base + 10240))[(j * 16 + l15) * 40 + q * 8];
      bf16x8 bn = *(const bf16x8*)&((us*)(base + 15360))[(j * 16 + l15) * 40 + q * 8];
      aR[j] = __builtin_amdgcn_mfma_f32_16x16x32_bf16(a, br, aR[j], 0, 0, 0);
      aZ[j] = __builtin_amdgcn_mfma_f32_16x16x32_bf16(a, bz, aZ[j], 0, 0, 0);
      aI[j] = __builtin_amdgcn_mfma_f32_16x16x32_bf16(a, bn, aI[j], 0, 0, 0);
    }
    if (more) {
      char* nb = smemc + (cur ^ 1) * 20480;
      *(uint4*)&((us*)nb)[srow * 40 + scb] = av;
      *(uint4*)&((us*)(nb + 5120))[srow * 40 + scb] = rv;
      *(uint4*)&((us*)(nb + 10240))[srow * 40 + scb] = zv;
      *(uint4*)&((us*)(nb + 15360))[srow * 40 + scb] = nv;
    }
    __syncthreads();
  }
  #pragma unroll
  for (int j = 0; j < 4; ++j) {
    const int c = c0 + j * 16 + l15;
    const float bR = bih[c] + bhh[c];
    const float bZ = bih[Hn + c] + bhh[Hn + c];
    const float bI = bih[2 * Hn + c];
    const float bH = bhh[2 * Hn + c];
    #pragma unroll
    for (int r = 0; r < 4; ++r) {
      const int m = m0 + w * 16 + q * 4 + r;
      const float h = b2f(hprev[(size_t)m * Hn + c]);
      const float rg = sigmf(aR[j][r] + bR);
      const float zg = sigmf(aZ[j][r] + bZ);
      const float ng = tanhf(aI[j][r] + bI + rg * (aH[j][r] + bH));
      hnew[(size_t)m * Hn + c] = f2b((1.0f - zg) * ng + zg * h);
    }
  }
}

// decoder GEMM tile + fused BCE reduction. smem >= 20496 B.
__device__ void tile_nll(
    int bx, int by, const us* dec, const us* dmW, const float* dmb,
    const float* xt, float* nll, char* smemc)
{
  float* red = (float*)(smemc + 20480);
  const int tid = threadIdx.x, srow = tid >> 2, scb = (tid & 3) * 8;
  const int lane = tid & 63, w = tid >> 6, l15 = lane & 15, q = lane >> 4;
  const int m0 = by * 64, n0 = bx * 64;
  f32x4 acc[4];
  #pragma unroll
  for (int j = 0; j < 4; ++j) acc[j] = (f32x4){0.f, 0.f, 0.f, 0.f};
  const int wrow = (n0 + srow < Xn) ? (n0 + srow) : (Xn - 1);
  const us* ap = dec + (size_t)(m0 + srow) * Hn + scb;
  const us* wp = dmW + (size_t)wrow * Hn + scb;
  uint4 av = *(const uint4*)ap;
  uint4 wv = *(const uint4*)wp;
  *(uint4*)&((us*)smemc)[srow * 40 + scb] = av;
  *(uint4*)&((us*)(smemc + 5120))[srow * 40 + scb] = wv;
  __syncthreads();
  for (int kt = 0; kt < 16; ++kt) {
    const int cur = kt & 1;
    us* Asc = (us*)(smemc + cur * 10240);
    us* Bsc = (us*)(smemc + cur * 10240 + 5120);
    const bool more = (kt + 1 < 16);
    if (more) {
      av = *(const uint4*)(ap + (kt + 1) * 32);
      wv = *(const uint4*)(wp + (kt + 1) * 32);
    }
    bf16x8 a = *(const bf16x8*)&Asc[(w * 16 + l15) * 40 + q * 8];
    #pragma unroll
    for (int j = 0; j < 4; ++j) {
      bf16x8 b = *(const bf16x8*)&Bsc[(j * 16 + l15) * 40 + q * 8];
      acc[j] = __builtin_amdgcn_mfma_f32_16x16x32_bf16(a, b, acc[j], 0, 0, 0);
    }
    if (more) {
      *(uint4*)&((us*)(smemc + (cur ^ 1) * 10240))[srow * 40 + scb] = av;
      *(uint4*)&((us*)(smemc + (cur ^ 1) * 10240 + 5120))[srow * 40 + scb] = wv;
    }
    __syncthreads();
  }
  float sum = 0.0f;
  #pragma unroll
  for (int j = 0; j < 4; ++j) {
    const int n = n0 + j * 16 + l15;
    if (n < Xn) {
      const float bv = dmb[n];
      #pragma unroll
      for (int r = 0; r < 4; ++r) {
        const int m = m0 + w * 16 + q * 4 + r;
        const float a = acc[j][r] + bv;
        const float xv = xt[(size_t)m * Xn + n];
        sum += splusf(-a) + (1.0f - xv) * a;
      }
    }
  }
  const float s = block_sum(sum, red);
  if (tid == 0) atomicAdd(nll, s);
}

// dual-head stats (MODE 0: prior stats fp32; MODE 1: f sample + f_kld). smem >= 30736 B.
template <int MODE>
__device__ void stat_dual(int vb,
    const us* Ain, const us* Wm, const float* bm, const us* Ws, const float* bs,
    const float* eps, us* o0b, float* o_pm, float* o_ps, float* kacc, char* smemc)
{
  float* red = (float*)(smemc + 30720);
  const int tid = threadIdx.x, srow = tid >> 2, scb = (tid & 3) * 8;
  const int lane = tid & 63, w = tid >> 6, l15 = lane & 15, q = lane >> 4;
  const int m0 = vb * 64;
  f32x4 am[4], as_[4];
  #pragma unroll
  for (int j = 0; j < 4; ++j) { am[j] = (f32x4){0.f, 0.f, 0.f, 0.f}; as_[j] = am[j]; }
  const us* ap = Ain + (size_t)(m0 + srow) * Hn + scb;
  const us* mp = Wm + (size_t)srow * Hn + scb;
  const us* sp = Ws + (size_t)srow * Hn + scb;
  uint4 av = *(const uint4*)ap;
  uint4 mv = *(const uint4*)mp;
  uint4 sv = *(const uint4*)sp;
  *(uint4*)&((us*)smemc)[srow * 40 + scb] = av;
  *(uint4*)&((us*)(smemc + 5120))[srow * 40 + scb] = mv;
  *(uint4*)&((us*)(smemc + 10240))[srow * 40 + scb] = sv;
  __syncthreads();
  for (int kt = 0; kt < 16; ++kt) {
    const int cur = kt & 1;
    char* base = smemc + cur * 15360;
    const bool more = (kt + 1 < 16);
    if (more) {
      av = *(const uint4*)(ap + (kt + 1) * 32);
      mv = *(const uint4*)(mp + (kt + 1) * 32);
      sv = *(const uint4*)(sp + (kt + 1) * 32);
    }
    bf16x8 a = *(const bf16x8*)&((us*)base)[(w * 16 + l15) * 40 + q * 8];
    #pragma unroll
    for (int j = 0; j < 4; ++j) {
      bf16x8 b0 = *(const bf16x8*)&((us*)(base + 5120))[(j * 16 + l15) * 40 + q * 8];
      bf16x8 b1 = *(const bf16x8*)&((us*)(base + 10240))[(j * 16 + l15) * 40 + q * 8];
      am[j]  = __builtin_amdgcn_mfma_f32_16x16x32_bf16(a, b0, am[j], 0, 0, 0);
      as_[j] = __builtin_amdgcn_mfma_f32_16x16x32_bf16(a, b1, as_[j], 0, 0, 0);
    }
    if (more) {
      char* nb = smemc + ((cur ^ 1) * 15360);
      *(uint4*)&((us*)nb)[srow * 40 + scb] = av;
      *(uint4*)&((us*)(nb + 5120))[srow * 40 + scb] = mv;
      *(uint4*)&((us*)(nb + 10240))[srow * 40 + scb] = sv;
    }
    __syncthreads();
  }
  float kld = 0.0f;
  #pragma unroll
  for (int j = 0; j < 4; ++j) {
    const int c = j * 16 + l15;
    const float bmv = bm[c], bsv = bs[c];
    #pragma unroll
    for (int r = 0; r < 4; ++r) {
      const int m = m0 + w * 16 + q * 4 + r;
      const float mu = am[j][r] + bmv;
      const float sd = splusf(as_[j][r] + bsv);
      if (MODE == 0) {
        o_pm[(size_t)m * Zn + c] = mu;
        o_ps[(size_t)m * Zn + c] = sd;
      } else {
        o0b[(size_t)m * Zn + c] = f2b(eps[(size_t)m * Zn + c] * sd + mu);
        kld += mu * mu + sd * sd - 2.0f * __logf(sd) - 1.0f;
      }
    }
  }
  if (MODE != 0) {
    const float s = block_sum(kld, red);
    if (tid == 0) atomicAdd(kacc, 0.5f * s);
  }
}

// enc stats + z_kld + fused phiz GEMM (zt kept in LDS). smem >= 39952 B.
__device__ void statphiz(int vb,
    const us* ze, const us* Wm, const float* bm, const us* Ws, const float* bs,
    const float* eps, const float* zpm, const float* zps,
    const us* pzW, const float* pzb, us* phiz, float* kacc, char* smemc)
{
  us* ztL = (us*)(smemc + 30720);        // [64][72]
  float* red = (float*)(smemc + 39936);
  const int tid = threadIdx.x, srow = tid >> 2, scb = (tid & 3) * 8;
  const int lane = tid & 63, w = tid >> 6, l15 = lane & 15, q = lane >> 4;
  const int m0 = vb * 64;
  f32x4 am[4], as_[4];
  #pragma unroll
  for (int j = 0; j < 4; ++j) { am[j] = (f32x4){0.f, 0.f, 0.f, 0.f}; as_[j] = am[j]; }
  const us* ap = ze + (size_t)(m0 + srow) * Hn + scb;
  const us* mp = Wm + (size_t)srow * Hn + scb;
  const us* sp = Ws + (size_t)srow * Hn + scb;
  uint4 av = *(const uint4*)ap;
  uint4 mv = *(const uint4*)mp;
  uint4 sv = *(const uint4*)sp;
  *(uint4*)&((us*)smemc)[srow * 40 + scb] = av;
  *(uint4*)&((us*)(smemc + 5120))[srow * 40 + scb] = mv;
  *(uint4*)&((us*)(smemc + 10240))[srow * 40 + scb] = sv;
  __syncthreads();
  for (int kt = 0; kt < 16; ++kt) {
    const int cur = kt & 1;
    char* base = smemc + cur * 15360;
    const bool more = (kt + 1 < 16);
    if (more) {
      av = *(const uint4*)(ap + (kt + 1) * 32);
      mv = *(const uint4*)(mp + (kt + 1) * 32);
      sv = *(const uint4*)(sp + (kt + 1) * 32);
    }
    bf16x8 a = *(const bf16x8*)&((us*)base)[(w * 16 + l15) * 40 + q * 8];
    #pragma unroll
    for (int j = 0; j < 4; ++j) {
      bf16x8 b0 = *(const bf16x8*)&((us*)(base + 5120))[(j * 16 + l15) * 40 + q * 8];
      bf16x8 b1 = *(const bf16x8*)&((us*)(base + 10240))[(j * 16 + l15) * 40 + q * 8];
      am[j]  = __builtin_amdgcn_mfma_f32_16x16x32_bf16(a, b0, am[j], 0, 0, 0);
      as_[j] = __builtin_amdgcn_mfma_f32_16x16x32_bf16(a, b1, as_[j], 0, 0, 0);
    }
    if (more) {
      char* nb = smemc + ((cur ^ 1) * 15360);
      *(uint4*)&((us*)nb)[srow * 40 + scb] = av;
      *(uint4*)&((us*)(nb + 5120))[srow * 40 + scb] = mv;
      *(uint4*)&((us*)(nb + 10240))[srow * 40 + scb] = sv;
    }
    __syncthreads();
  }
  float kld = 0.0f;
  #pragma unroll
  for (int j = 0; j < 4; ++j) {
    const int c = j * 16 + l15;
    const float bmv = bm[c], bsv = bs[c];
    #pragma unroll
    for (int r = 0; r < 4; ++r) {
      const int row = w * 16 + q * 4 + r;
      const int m = m0 + row;
      const float mu = am[j][r] + bmv;
      const float sd = splusf(as_[j][r] + bsv);
      ztL[row * 72 + c] = f2b(eps[(size_t)m * Zn + c] * sd + mu);
      const float pm = zpm[(size_t)m * Zn + c];
      const float ps = zps[(size_t)m * Zn + c];
      const float dd = (mu - pm) / ps;
      const float rr = sd / ps;
      kld += dd * dd + rr * rr - 2.0f * __logf(rr) - 1.0f;
    }
  }
  const float s = block_sum(kld, red);   // syncthreads inside -> ztL visible
  if (tid == 0) atomicAdd(kacc, 0.5f * s);
  // gamma: phiz = relu(ztL @ pzW^T + pzb), K=64, 8 col-chunks
  us* G = (us*)smemc;
  for (int cc = 0; cc < 8; ++cc) {
    f32x4 acc[4];
    #pragma unroll
    for (int j = 0; j < 4; ++j) acc[j] = (f32x4){0.f, 0.f, 0.f, 0.f};
    #pragma unroll
    for (int k0 = 0; k0 < 64; k0 += 32) {
      uint4 wv = *(const uint4*)(pzW + (size_t)(cc * 64 + srow) * 64 + k0 + scb);
      __syncthreads();
      *(uint4*)&G[srow * 40 + scb] = wv;
      __syncthreads();
      bf16x8 a = *(const bf16x8*)&ztL[(w * 16 + l15) * 72 + k0 + q * 8];
      #pragma unroll
      for (int j = 0; j < 4; ++j) {
        bf16x8 b = *(const bf16x8*)&G[(j * 16 + l15) * 40 + q * 8];
        acc[j] = __builtin_amdgcn_mfma_f32_16x16x32_bf16(a, b, acc[j], 0, 0, 0);
      }
    }
    #pragma unroll
    for (int j = 0; j < 4; ++j) {
      const int col = cc * 64 + j * 16 + l15;
      const float bz = pzb[col];
      #pragma unroll
      for (int r = 0; r < 4; ++r) {
        const int row = w * 16 + q * 4 + r;
        phiz[(size_t)(m0 + row) * Hn + col] = f2b(fmaxf(acc[j][r] + bz, 0.f));
      }
    }
  }
}

// ================= global kernels =================
__global__ __launch_bounds__(256) void g_A1(
    const float* X, const us* W, const float* bias, us* C)
{
  __shared__ alignas(16) char sm[20480];
  tile_gA1(blockIdx.x, blockIdx.y, X, W, bias, C, sm);
}

__global__ __launch_bounds__(256) void g_gemm(
    const us* A, const us* W, int ldw, int K, const float* bias, us* C, int ldc)
{
  __shared__ alignas(16) char sm[20480];
  tile_gemmx<1, true, false, false, true>(blockIdx.x, blockIdx.y, A, W, ldw, K,
      nullptr, nullptr, 0, 0, nullptr, 0, bias, C, ldc, sm);
}

__global__ __launch_bounds__(256) void g_gruB(
    const us* A0, const us* Wih, const us* hprev, const us* Whh,
    const float* bih, const float* bhh, us* hnew)
{
  __shared__ alignas(16) char sm[40960];
  tile_gru_fe(blockIdx.x, blockIdx.y, A0, Wih, hprev, Whh, bih, bhh, hnew, sm);
}

__global__ __launch_bounds__(256) void g_statf(
    const us* fh, const us* femW, const float* femb, const us* fesW, const float* fesb,
    const float* eps_f, us* fbuf, float* kacc)
{
  __shared__ alignas(16) char sm[30736];
  stat_dual<1>(blockIdx.x, fh, femW, femb, fesW, fesb, eps_f,
               fbuf, nullptr, nullptr, kacc, sm);
}

// P23: Cpre_gru(192) | Cpre_dec(64) | zp0(64) | zepre0(64)  = 384 blocks
__global__ __launch_bounds__(256) void g_P23(
    const us* phi_f, const us* rWih, const us* dW1, const float* db1,
    float* Cpre_gru, float* Cpre_dec,
    const us* h0, const us* zpW, const float* zpb, us* zp,
    const us* px0, const us* zeW1, const float* zeb1, us* zepre)
{
  __shared__ alignas(16) char sm[20480];
  const int b = blockIdx.x;
  if (b < 192)
    tile_gemmx<1, false, true, false, false>(b % 24, b / 24, phi_f, rWih + 1024, 1536, Hn,
        nullptr, nullptr, 0, 0, nullptr, 0, nullptr, Cpre_gru, 1536, sm);
  else if (b < 256)
    tile_gemmx<1, false, true, false, true>((b - 192) & 7, (b - 192) >> 3,
        phi_f, dW1 + 512, 1536, Hn, nullptr, nullptr, 0, 0,
        nullptr, 0, db1, Cpre_dec, 512, sm);
  else if (b < 320)
    tile_gemmx<1, true, false, false, true>((b - 256) & 7, (b - 256) >> 3, h0, zpW, Hn, Hn,
        nullptr, nullptr, 0, 0, nullptr, 0, zpb, zp, Hn, sm);
  else
    tile_gemmx<2, true, false, false, true>((b - 320) & 7, (b - 320) >> 3,
        px0, zeW1, 1024, Hn, h0, zeW1 + 512, 1024, Hn,
        nullptr, 0, zeb1, zepre, Hn, sm);
}

// P4: ze0(64) | zpstat0(8)
__global__ __launch_bounds__(256) void g_P4(
    const us* zepre, const us* zeW2, const float* zeb2, us* ze,
    const us* zp, const us* zpmW, const float* zpmb, const us* zpsW, const float* zpsb,
    float* zpm, float* zps)
{
  __shared__ alignas(16) char sm[30736];
  const int b = blockIdx.x;
  if (b < 64)
    tile_gemmx<1, true, false, false, true>(b & 7, b >> 3, zepre, zeW2, Hn, Hn,
        nullptr, nullptr, 0, 0, nullptr, 0, zeb2, ze, Hn, sm);
  else
    stat_dual<0>(b - 64, zp, zpmW, zpmb, zpsW, zpsb,
                 nullptr, nullptr, zpm, zps, nullptr, sm);
}

// Stage A: statphiz(8) | gipre(192)
__global__ __launch_bounds__(256) void g_A(
    const us* ze, const us* zemW, const float* zemb, const us* zesW, const float* zesb,
    const float* eps_zt, const float* zpm, const float* zps,
    const us* pzW, const float* pzb, us* phiz, float* kacc,
    const us* px_t, const us* rWih, const float* Cpre_gru, float* gipre)
{
  __shared__ alignas(16) char sm[40960];
  const int b = blockIdx.x;
  if (b < 8)
    statphiz(b, ze, zemW, zemb, zesW, zesb, eps_zt, zpm, zps,
             pzW, pzb, phiz, kacc, sm);
  else {
    const int tb = b - 8;
    tile_gemmx<1, false, true, true, false>(tb % 24, tb / 24, px_t, rWih, 1536, Hn,
        nullptr, nullptr, 0, 0, Cpre_gru, 1536, nullptr, gipre, 1536, sm);
  }
}

// Stage B: gru_fin(64) | dtmp(64)
__global__ __launch_bounds__(256) void g_B(
    const us* phiz, const us* rWih, const float* gipre, const float* ghpre,
    const us* hprev, const float* rbih, const float* rbhh, us* hnew,
    const us* dW1, const float* dtmph, us* dtmp)
{
  __shared__ alignas(16) char sm[40960];
  const int b = blockIdx.x;
  if (b < 64)
    tile_gru_fin(b & 7, b >> 3, phiz, rWih, gipre, ghpre, hprev, rbih, rbhh, hnew, sm);
  else
    tile_gemmx<1, true, false, true, false>((b - 64) & 7, (b - 64) >> 3, phiz, dW1, 1536, Hn,
        nullptr, nullptr, 0, 0, dtmph, 512, nullptr, dtmp, Hn, sm);
}

// Stage C: dec(64) | zp'(64) | zepre'(64) | dtmph'(64)
__global__ __launch_bounds__(256) void g_C(
    const us* dtmp, const us* dW2, const float* db2, us* dec,
    const us* hnext, const us* zpW, const float* zpb, us* zp,
    const us* px1, const us* zeW1, const float* zeb1, us* zepre,
    const us* dW1, const float* Cpre_dec, float* dtmph)
{
  __shared__ alignas(16) char sm[20480];
  const int b = blockIdx.x;
  if (b < 64)
    tile_gemmx<1, true, false, false, true>(b & 7, b >> 3, dtmp, dW2, Hn, Hn,
        nullptr, nullptr, 0, 0, nullptr, 0, db2, dec, Hn, sm);
  else if (b < 128)
    tile_gemmx<1, true, false, false, true>((b - 64) & 7, (b - 64) >> 3, hnext, zpW, Hn, Hn,
        nullptr, nullptr, 0, 0, nullptr, 0, zpb, zp, Hn, sm);
  else if (b < 192)
    tile_gemmx<2, true, false, false, true>((b - 128) & 7, (b - 128) >> 3,
        px1, zeW1, 1024, Hn, hnext, zeW1 + 512, 1024, Hn,
        nullptr, 0, zeb1, zepre, Hn, sm);
  else
    tile_gemmx<1, false, true, true, false>((b - 192) & 7, (b - 192) >> 3,
        hnext, dW1 + 1024, 1536, Hn, nullptr, nullptr, 0, 0,
        Cpre_dec, 512, nullptr, dtmph, 512, sm);
}

// Stage D: nll(104) | ze'(64) | zpstat'(8) | ghpre'(192)
__global__ __launch_bounds__(256) void g_D(
    const us* dec, const us* dmW, const float* dmb, const float* xt, float* nll,
    const us* zepre, const us* zeW2, const float* zeb2, us* ze,
    const us* zp, const us* zpmW, const float* zpmb, const us* zpsW, const float* zpsb,
    float* zpm, float* zps,
    const us* hnext, const us* rWhh, float* ghpre)
{
  __shared__ alignas(16) char sm[30736];
  const int b = blockIdx.x;
  if (b < 104)
    tile_nll(b % 13, b / 13, dec, dmW, dmb, xt, nll, sm);
  else if (b < 168)
    tile_gemmx<1, true, false, false, true>((b - 104) & 7, (b - 104) >> 3, zepre, zeW2, Hn, Hn,
        nullptr, nullptr, 0, 0, nullptr, 0, zeb2, ze, Hn, sm);
  else if (b < 176)
    stat_dual<0>(b - 168, zp, zpmW, zpmb, zpsW, zpsb,
                 nullptr, nullptr, zpm, zps, nullptr, sm);
  else {
    const int tb = b - 176;
    tile_gemmx<1, false, true, false, false>(tb % 24, tb / 24, hnext, rWhh, Hn, Hn,
        nullptr, nullptr, 0, 0, nullptr, 0, nullptr, ghpre, 1536, sm);
  }
}

} // anonymous namespace

extern "C" void kernel_launch(void* const* d_in, const int* in_sizes, int n_in,
                              void* d_out, int out_size, void* d_ws, size_t ws_size,
                              hipStream_t stream)
{
  (void)in_sizes; (void)n_in; (void)out_size; (void)ws_size;
  const float* x     = (const float*)d_in[0];
  const float* eps_f = (const float*)d_in[1];
  const float* eps_z = (const float*)d_in[2];
  const float* pxW1  = (const float*)d_in[3];
  const float* pxb1  = (const float*)d_in[4];
  const float* pxW2  = (const float*)d_in[5];
  const float* pxb2  = (const float*)d_in[6];
  const float* pzW   = (const float*)d_in[7];
  const float* pzb   = (const float*)d_in[8];
  const float* pfW   = (const float*)d_in[9];
  const float* pfb   = (const float*)d_in[10];
  const float* rWih  = (const float*)d_in[11];
  const float* rWhh  = (const float*)d_in[12];
  const float* rbih  = (const float*)d_in[13];
  const float* rbhh  = (const float*)d_in[14];
  const float* zpW   = (const float*)d_in[15];
  const float* zpb   = (const float*)d_in[16];
  const float* zpmW  = (const float*)d_in[17];
  const float* zpmb  = (const float*)d_in[18];
  const float* zpsW  = (const float*)d_in[19];
  const float* zpsb  = (const float*)d_in[20];
  const float* feWih = (const float*)d_in[21];
  const float* feWhh = (const float*)d_in[22];
  const float* febih = (const float*)d_in[23];
  const float* febhh = (const float*)d_in[24];
  const float* femW  = (const float*)d_in[25];
  const float* femb  = (const float*)d_in[26];
  const float* fesW  = (const float*)d_in[27];
  const float* fesb  = (const float*)d_in[28];
  const float* zeW1  = (const float*)d_in[29];
  const float* zeb1  = (const float*)d_in[30];
  const float* zeW2  = (const float*)d_in[31];
  const float* zeb2  = (const float*)d_in[32];
  const float* zemW  = (const float*)d_in[33];
  const float* zemb  = (const float*)d_in[34];
  const float* zesW  = (const float*)d_in[35];
  const float* zesb  = (const float*)d_in[36];
  const float* dW1   = (const float*)d_in[37];
  const float* db1   = (const float*)d_in[38];
  const float* dW2   = (const float*)d_in[39];
  const float* db2   = (const float*)d_in[40];
  const float* dmW   = (const float*)d_in[41];
  const float* dmb   = (const float*)d_in[42];
  float* out = (float*)d_out;

  char* base = (char*)d_ws;
  size_t off = 0;
  auto ab = [&](size_t bytes) -> void* {
    void* p = base + off;
    off += (bytes + 255) & ~(size_t)255;
    return p;
  };

  // bf16 weights
  us* b_pxW1  = (us*)ab((size_t)512 * XnP * 2);
  us* b_pxW2  = (us*)ab((size_t)512 * 512 * 2);
  us* b_pzW   = (us*)ab((size_t)512 * 64 * 2);
  us* b_pfW   = (us*)ab((size_t)512 * 64 * 2);
  us* b_rWih  = (us*)ab((size_t)1536 * 1536 * 2);
  us* b_rWhh  = (us*)ab((size_t)1536 * 512 * 2);
  us* b_zpW   = (us*)ab((size_t)512 * 512 * 2);
  us* b_zpmW  = (us*)ab((size_t)64 * 512 * 2);
  us* b_zpsW  = (us*)ab((size_t)64 * 512 * 2);
  us* b_feWih = (us*)ab((size_t)1536 * 512 * 2);
  us* b_feWhh = (us*)ab((size_t)1536 * 512 * 2);
  us* b_femW  = (us*)ab((size_t)64 * 512 * 2);
  us* b_fesW  = (us*)ab((size_t)64 * 512 * 2);
  us* b_zeW1  = (us*)ab((size_t)512 * 1024 * 2);
  us* b_zeW2  = (us*)ab((size_t)512 * 512 * 2);
  us* b_zemW  = (us*)ab((size_t)64 * 512 * 2);
  us* b_zesW  = (us*)ab((size_t)64 * 512 * 2);
  us* b_dW1   = (us*)ab((size_t)512 * 1536 * 2);
  us* b_dW2   = (us*)ab((size_t)512 * 512 * 2);
  us* b_dmW   = (us*)ab((size_t)Xn * 512 * 2);

  // activations
  us* phi_x = (us*)ab((size_t)Tn * Bn * Hn * 2);
  us* tmpA  = (us*)ab((size_t)Tn * Bn * Hn * 2);
  us* fh_a  = (us*)ab((size_t)Bn * Hn * 2);
  us* h_a   = (us*)ab((size_t)Bn * Hn * 2);   // adjacent to fh_a (one memset)
  us* fh_b  = (us*)ab((size_t)Bn * Hn * 2);
  us* h_b   = (us*)ab((size_t)Bn * Hn * 2);
  us* fbuf  = (us*)ab((size_t)Bn * Fn * 2);
  us* phi_f = (us*)ab((size_t)Bn * Hn * 2);
  us* zp    = (us*)ab((size_t)Bn * Hn * 2);
  us* zepre = (us*)ab((size_t)Bn * Hn * 2);
  us* ze    = (us*)ab((size_t)Bn * Hn * 2);
  us* phiz  = (us*)ab((size_t)Bn * Hn * 2);
  us* dtmp  = (us*)ab((size_t)Bn * Hn * 2);
  us* dec   = (us*)ab((size_t)Bn * Hn * 2);
  float* zpm = (float*)ab((size_t)Bn * Zn * 4);
  float* zps = (float*)ab((size_t)Bn * Zn * 4);
  float* Cpre_gru = (float*)ab((size_t)Bn * 1536 * 4);
  float* Cpre_dec = (float*)ab((size_t)Bn * 512 * 4);
  float* gipre    = (float*)ab((size_t)Bn * 1536 * 4);
  float* ghpre    = (float*)ab((size_t)Bn * 1536 * 4);
  float* dtmph    = (float*)ab((size_t)Bn * 512 * 4);

  hipMemsetAsync(d_out, 0, 3 * sizeof(float), stream);
  hipMemsetAsync(fh_a, 0, 2 * (size_t)Bn * Hn * 2, stream);    // fh_a + h_a
  hipMemsetAsync(ghpre, 0, (size_t)Bn * 1536 * 4, stream);     // gh(h0=0)=0

  const dim3 blk(256);
  auto CVT = [&](const float* s, us* d, size_t n) {
    cvt<<<dim3((unsigned)((n + 255) / 256)), blk, 0, stream>>>(s, d, (int)n);
  };

  {
    const size_t n = (size_t)512 * XnP;
    cvt_pad<<<dim3((unsigned)((n + 255) / 256)), blk, 0, stream>>>(pxW1, b_pxW1, Xn, XnP, (int)n);
  }
  CVT(pxW2, b_pxW2, (size_t)512 * 512);
  CVT(pzW, b_pzW, (size_t)512 * 64);
  CVT(pfW, b_pfW, (size_t)512 * 64);
  CVT(rWih, b_rWih, (size_t)1536 * 1536);
  CVT(rWhh, b_rWhh, (size_t)1536 * 512);
  CVT(zpW, b_zpW, (size_t)512 * 512);
  CVT(zpmW, b_zpmW, (size_t)64 * 512);
  CVT(zpsW, b_zpsW, (size_t)64 * 512);
  CVT(feWih, b_feWih, (size_t)1536 * 512);
  CVT(feWhh, b_feWhh, (size_t)1536 * 512);
  CVT(femW, b_femW, (size_t)64 * 512);
  CVT(fesW, b_fesW, (size_t)64 * 512);
  CVT(zeW1, b_zeW1, (size_t)512 * 1024);
  CVT(zeW2, b_zeW2, (size_t)512 * 512);
  CVT(zemW, b_zemW, (size_t)64 * 512);
  CVT(zesW, b_zesW, (size_t)64 * 512);
  CVT(dW1, b_dW1, (size_t)512 * 1536);
  CVT(dW2, b_dW2, (size_t)512 * 512);
  CVT(dmW, b_dmW, (size_t)Xn * 512);

  // ---- Phase A: phi_x = relu(relu(x@pxW1^T+b)@pxW2^T+b), all T at once ----
  g_A1<<<dim3(8, Tn * Bn / 64), blk, 0, stream>>>(x, b_pxW1, pxb1, tmpA);
  g_gemm<<<dim3(8, Tn * Bn / 64), blk, 0, stream>>>(tmpA, b_pxW2, Hn, Hn, pxb2, phi_x, Hn);

  // ---- Phase B: f-encoder GRU ----
  us* fc = fh_a; us* fn2 = fh_b;
  for (int t = 0; t < Tn; ++t) {
    g_gruB<<<dim3(8, 8), blk, 0, stream>>>(
        phi_x + (size_t)t * Bn * Hn, b_feWih, fc, b_feWhh, febih, febhh, fn2);
    us* sw = fc; fc = fn2; fn2 = sw;
  }

  // ---- Phase C: f stats (Tn even -> final hidden in fh_a) ----
  g_statf<<<dim3(8), blk, 0, stream>>>(fh_a, b_femW, femb, b_fesW, fesb, eps_f, fbuf, out + 0);

  // ---- Prologue ----
  g_gemm<<<dim3(8, 8), blk, 0, stream>>>(fbuf, b_pfW, Fn, Fn, pfb, phi_f, Hn);
  g_P23<<<dim3(384), blk, 0, stream>>>(phi_f, b_rWih, b_dW1, db1, Cpre_gru, Cpre_dec,
                                       h_a, b_zpW, zpb, zp, phi_x, b_zeW1, zeb1, zepre);
  g_P4<<<dim3(72), blk, 0, stream>>>(zepre, b_zeW2, zeb2, ze,
                                     zp, b_zpmW, zpmb, b_zpsW, zpsb, zpm, zps);

  // ---- Phase D: 4 launches per timestep ----
  for (int t = 0; t < Tn; ++t) {
    const us* hcur = (t & 1) ? h_b : h_a;
    us* hnext      = (t & 1) ? h_a : h_b;
    const bool last = (t == Tn - 1);
    const us* px_t = phi_x + (size_t)t * Bn * Hn;
    const float* dtmph_sel = (t == 0) ? Cpre_dec : dtmph;

    g_A<<<dim3(200), blk, 0, stream>>>(
        ze, b_zemW, zemb, b_zesW, zesb, eps_z + (size_t)t * Bn * Zn, zpm, zps,
        b_pzW, pzb, phiz, out + 1, px_t, b_rWih, Cpre_gru, gipre);

    g_B<<<dim3(128), blk, 0, stream>>>(
        phiz, b_rWih, gipre, ghpre, hcur, rbih, rbhh, hnext,
        b_dW1, dtmph_sel, dtmp);

    g_C<<<dim3(last ? 64 : 256), blk, 0, stream>>>(
        dtmp, b_dW2, db2, dec, hnext, b_zpW, zpb, zp,
        phi_x + (size_t)(t + 1) * Bn * Hn, b_zeW1, zeb1, zepre,
        b_dW1, Cpre_dec, dtmph);

    g_D<<<dim3(last ? 104 : 368), blk, 0, stream>>>(
        dec, b_dmW, dmb, x + (size_t)t * Bn * Xn, out + 2,
        zepre, b_zeW2, zeb2, ze,
        zp, b_zpmW, zpmb, b_zpsW, zpsb, zpm, zps,
        hnext, b_rWhh, ghpre);
  }
}

// Round 7
// 6853.637 us; speedup vs baseline: 1.0624x; 1.0624x over previous
//
#include <hip/hip_runtime.h>
#include <cmath>

namespace {

constexpr int Tn = 64;
constexpr int Bn = 512;
constexpr int Xn = 784;
constexpr int XnP = 800;
constexpr int Fn = 64;
constexpr int Zn = 64;
constexpr int Hn = 512;

typedef unsigned short us;
typedef __attribute__((ext_vector_type(8))) short bf16x8;
typedef __attribute__((ext_vector_type(4))) float f32x4;

__device__ __forceinline__ us f2b(float v) {
  unsigned int u = __float_as_uint(v);
  return (us)((u + 0x7FFFu + ((u >> 16) & 1u)) >> 16);
}
__device__ __forceinline__ float b2f(us u) { return __uint_as_float(((unsigned int)u) << 16); }
__device__ __forceinline__ float sigmf(float v) { return 1.0f / (1.0f + __expf(-v)); }
__device__ __forceinline__ float splusf(float v) {
  return v > 0.0f ? (v + log1pf(__expf(-v))) : log1pf(__expf(v));
}
__device__ __forceinline__ float block_sum(float v, float* red) {
  #pragma unroll
  for (int off = 32; off > 0; off >>= 1) v += __shfl_down(v, off, 64);
  if ((threadIdx.x & 63) == 0) red[threadIdx.x >> 6] = v;
  __syncthreads();
  float s = 0.0f;
  if (threadIdx.x == 0) s = red[0] + red[1] + red[2] + red[3];
  return s;
}

// ---- converters (weights only) ----
__global__ void cvt(const float* __restrict__ s, us* __restrict__ d, int n) {
  int i = blockIdx.x * 256 + threadIdx.x;
  if (i < n) d[i] = f2b(s[i]);
}
__global__ void cvt_pad(const float* __restrict__ s, us* __restrict__ d, int C, int Cp, int n) {
  int i = blockIdx.x * 256 + threadIdx.x;
  if (i < n) {
    int r = i / Cp, c = i - r * Cp;
    d[i] = (c < C) ? f2b(s[(size_t)r * C + c]) : (us)0;
  }
}

// ================= tile device functions (R5 two-barrier style) =================
// 64x64 GEMM tile: C = act(sum_seg A.W^T [+init] [+bias]).
// IMODE: 0 = zero-init, 1 = fp32 pre-accumulator (initF), 2 = bf16 epilogue add (initB).
// smem >= 10240 B.
template <int NSEG, bool RELU, bool F32OUT, int IMODE, bool HASBIAS>
__device__ void tile_gemmx(
    int bx, int by,
    const us* A0, const us* W0, int ldw0, int K0,
    const us* A1, const us* W1, int ldw1, int K1,
    const float* initF, const us* initB, int ldi, const float* bias,
    void* Cout, int ldc, char* smemc)
{
  us* As = (us*)smemc; us* Bs = (us*)(smemc + 5120);
  const int tid = threadIdx.x, srow = tid >> 2, scb = (tid & 3) * 8;
  const int lane = tid & 63, w = tid >> 6, l15 = lane & 15, q = lane >> 4;
  const int m0 = by * 64, n0 = bx * 64;
  f32x4 acc[4];
  if (IMODE == 1) {
    #pragma unroll
    for (int j = 0; j < 4; ++j)
      #pragma unroll
      for (int r = 0; r < 4; ++r)
        acc[j][r] = initF[(size_t)(m0 + w * 16 + q * 4 + r) * ldi + n0 + j * 16 + l15];
  } else {
    #pragma unroll
    for (int j = 0; j < 4; ++j) acc[j] = (f32x4){0.f, 0.f, 0.f, 0.f};
  }
  #pragma unroll
  for (int seg = 0; seg < NSEG; ++seg) {
    const us* A = (seg == 0) ? A0 : A1;
    const us* W = (seg == 0) ? W0 : W1;
    const int ldw = (seg == 0) ? ldw0 : ldw1;
    const int K   = (seg == 0) ? K0 : K1;
    const us* ap = A + (size_t)(m0 + srow) * K + scb;
    const us* wp = W + (size_t)(n0 + srow) * ldw + scb;
    uint4 av = *(const uint4*)ap;
    uint4 wv = *(const uint4*)wp;
    for (int k0 = 0; k0 < K; k0 += 32) {
      __syncthreads();
      *(uint4*)&As[srow * 40 + scb] = av;
      *(uint4*)&Bs[srow * 40 + scb] = wv;
      __syncthreads();
      if (k0 + 32 < K) {
        av = *(const uint4*)(ap + k0 + 32);
        wv = *(const uint4*)(wp + k0 + 32);
      }
      bf16x8 a = *(const bf16x8*)&As[(w * 16 + l15) * 40 + q * 8];
      #pragma unroll
      for (int j = 0; j < 4; ++j) {
        bf16x8 b = *(const bf16x8*)&Bs[(j * 16 + l15) * 40 + q * 8];
        acc[j] = __builtin_amdgcn_mfma_f32_16x16x32_bf16(a, b, acc[j], 0, 0, 0);
      }
    }
  }
  #pragma unroll
  for (int j = 0; j < 4; ++j) {
    const int col = n0 + j * 16 + l15;
    const float bv = HASBIAS ? bias[col] : 0.f;
    #pragma unroll
    for (int r = 0; r < 4; ++r) {
      const int row = m0 + w * 16 + q * 4 + r;
      float v = acc[j][r] + bv;
      if (IMODE == 2) v += b2f(initB[(size_t)row * ldi + col]);
      if (RELU) v = fmaxf(v, 0.f);
      if (F32OUT) ((float*)Cout)[(size_t)row * ldc + col] = v;
      else        ((us*)Cout)[(size_t)row * ldc + col] = f2b(v);
    }
  }
}

// Phase-A GEMM1: A read directly from fp32 x (cols clamped at 784), K=800 padded.
__device__ void tile_gA1(int bx, int by, const float* __restrict__ X, const us* W,
                         const float* bias, us* C, char* smemc)
{
  us* As = (us*)smemc; us* Bs = (us*)(smemc + 5120);
  const int tid = threadIdx.x, srow = tid >> 2, scb = (tid & 3) * 8;
  const int lane = tid & 63, w = tid >> 6, l15 = lane & 15, q = lane >> 4;
  const int m0 = by * 64, n0 = bx * 64;
  f32x4 acc[4];
  #pragma unroll
  for (int j = 0; j < 4; ++j) acc[j] = (f32x4){0.f, 0.f, 0.f, 0.f};
  auto ldA = [&](int k) -> uint4 {
    if (k + scb < Xn) {
      const float* p = X + (size_t)(m0 + srow) * Xn + k + scb;
      float4 f0 = *(const float4*)p;
      float4 f1 = *(const float4*)(p + 4);
      union { us h[8]; uint4 u; } pk;
      pk.h[0] = f2b(f0.x); pk.h[1] = f2b(f0.y); pk.h[2] = f2b(f0.z); pk.h[3] = f2b(f0.w);
      pk.h[4] = f2b(f1.x); pk.h[5] = f2b(f1.y); pk.h[6] = f2b(f1.z); pk.h[7] = f2b(f1.w);
      return pk.u;
    }
    return (uint4){0, 0, 0, 0};
  };
  const us* wp = W + (size_t)(n0 + srow) * XnP + scb;
  uint4 av = ldA(0);
  uint4 wv = *(const uint4*)wp;
  for (int k0 = 0; k0 < XnP; k0 += 32) {
    __syncthreads();
    *(uint4*)&As[srow * 40 + scb] = av;
    *(uint4*)&Bs[srow * 40 + scb] = wv;
    __syncthreads();
    if (k0 + 32 < XnP) {
      av = ldA(k0 + 32);
      wv = *(const uint4*)(wp + k0 + 32);
    }
    bf16x8 a = *(const bf16x8*)&As[(w * 16 + l15) * 40 + q * 8];
    #pragma unroll
    for (int j = 0; j < 4; ++j) {
      bf16x8 b = *(const bf16x8*)&Bs[(j * 16 + l15) * 40 + q * 8];
      acc[j] = __builtin_amdgcn_mfma_f32_16x16x32_bf16(a, b, acc[j], 0, 0, 0);
    }
  }
  #pragma unroll
  for (int j = 0; j < 4; ++j) {
    const int col = n0 + j * 16 + l15;
    const float bv = bias[col];
    #pragma unroll
    for (int r = 0; r < 4; ++r) {
      const int row = m0 + w * 16 + q * 4 + r;
      C[(size_t)row * Hn + col] = f2b(fmaxf(acc[j][r] + bv, 0.f));
    }
  }
}

// Phase-B GRU tile (2 segs: gi = A0@Wih^T, gh = h@Whh^T). smem >= 20480 B.
__device__ void tile_gru_fe(
    int bx, int by, const us* A0, const us* Wih,
    const us* hprev, const us* Whh,
    const float* bih, const float* bhh, us* hnew, char* smemc)
{
  us* Asm = (us*)smemc; us* Rs = (us*)(smemc + 5120);
  us* Zs = (us*)(smemc + 10240); us* Ns = (us*)(smemc + 15360);
  const int tid = threadIdx.x, srow = tid >> 2, scb = (tid & 3) * 8;
  const int lane = tid & 63, w = tid >> 6, l15 = lane & 15, q = lane >> 4;
  const int m0 = by * 64, c0 = bx * 64;
  f32x4 aR[4], aZ[4], aI[4], aH[4];
  #pragma unroll
  for (int j = 0; j < 4; ++j) {
    aR[j] = (f32x4){0.f, 0.f, 0.f, 0.f}; aZ[j] = aR[j]; aI[j] = aR[j]; aH[j] = aR[j];
  }
  #pragma unroll
  for (int seg = 0; seg < 2; ++seg) {
    const bool hseg = (seg == 1);
    const us* A  = hseg ? hprev : A0;
    const us* Wb = hseg ? Whh : Wih;
    const us* ap = A + (size_t)(m0 + srow) * Hn + scb;
    const us* wr = Wb + (size_t)(c0 + srow) * Hn + scb;
    const us* wz = wr + (size_t)Hn * Hn;
    const us* wn = wz + (size_t)Hn * Hn;
    uint4 av = *(const uint4*)ap;
    uint4 rv = *(const uint4*)wr;
    uint4 zv = *(const uint4*)wz;
    uint4 nv = *(const uint4*)wn;
    for (int k0 = 0; k0 < Hn; k0 += 32) {
      __syncthreads();
      *(uint4*)&Asm[srow * 40 + scb] = av;
      *(uint4*)&Rs[srow * 40 + scb] = rv;
      *(uint4*)&Zs[srow * 40 + scb] = zv;
      *(uint4*)&Ns[srow * 40 + scb] = nv;
      __syncthreads();
      if (k0 + 32 < Hn) {
        av = *(const uint4*)(ap + k0 + 32);
        rv = *(const uint4*)(wr + k0 + 32);
        zv = *(const uint4*)(wz + k0 + 32);
        nv = *(const uint4*)(wn + k0 + 32);
      }
      bf16x8 a = *(const bf16x8*)&Asm[(w * 16 + l15) * 40 + q * 8];
      #pragma unroll
      for (int j = 0; j < 4; ++j) {
        bf16x8 br = *(const bf16x8*)&Rs[(j * 16 + l15) * 40 + q * 8];
        bf16x8 bz = *(const bf16x8*)&Zs[(j * 16 + l15) * 40 + q * 8];
        bf16x8 bn = *(const bf16x8*)&Ns[(j * 16 + l15) * 40 + q * 8];
        aR[j] = __builtin_amdgcn_mfma_f32_16x16x32_bf16(a, br, aR[j], 0, 0, 0);
        aZ[j] = __builtin_amdgcn_mfma_f32_16x16x32_bf16(a, bz, aZ[j], 0, 0, 0);
        if (hseg) aH[j] = __builtin_amdgcn_mfma_f32_16x16x32_bf16(a, bn, aH[j], 0, 0, 0);
        else      aI[j] = __builtin_amdgcn_mfma_f32_16x16x32_bf16(a, bn, aI[j], 0, 0, 0);
      }
    }
  }
  #pragma unroll
  for (int j = 0; j < 4; ++j) {
    const int c = c0 + j * 16 + l15;
    const float bR = bih[c] + bhh[c];
    const float bZ = bih[Hn + c] + bhh[Hn + c];
    const float bI = bih[2 * Hn + c];
    const float bH = bhh[2 * Hn + c];
    #pragma unroll
    for (int r = 0; r < 4; ++r) {
      const int m = m0 + w * 16 + q * 4 + r;
      const float h = b2f(hprev[(size_t)m * Hn + c]);
      const float rg = sigmf(aR[j][r] + bR);
      const float zg = sigmf(aZ[j][r] + bZ);
      const float ng = tanhf(aI[j][r] + bI + rg * (aH[j][r] + bH));
      hnew[(size_t)m * Hn + c] = f2b((1.0f - zg) * ng + zg * h);
    }
  }
}

// Phase-D GRU final tile: phiz seg GEMM + fp32 preaccumulators. smem >= 20480 B.
__device__ void tile_gru_fin(
    int bx, int by, const us* phiz, const us* rWih,
    const float* gipre, const float* ghpre, const us* hprev,
    const float* bih, const float* bhh, us* hnew, char* smemc)
{
  us* Asm = (us*)smemc; us* Rs = (us*)(smemc + 5120);
  us* Zs = (us*)(smemc + 10240); us* Ns = (us*)(smemc + 15360);
  const int tid = threadIdx.x, srow = tid >> 2, scb = (tid & 3) * 8;
  const int lane = tid & 63, w = tid >> 6, l15 = lane & 15, q = lane >> 4;
  const int m0 = by * 64, c0 = bx * 64;
  f32x4 aR[4], aZ[4], aI[4];
  float aH[4][4];
  #pragma unroll
  for (int j = 0; j < 4; ++j) {
    const int c = c0 + j * 16 + l15;
    #pragma unroll
    for (int r = 0; r < 4; ++r) {
      const size_t row = (size_t)(m0 + w * 16 + q * 4 + r) * 1536;
      aR[j][r] = gipre[row + c] + ghpre[row + c];
      aZ[j][r] = gipre[row + 512 + c] + ghpre[row + 512 + c];
      aI[j][r] = gipre[row + 1024 + c];
      aH[j][r] = ghpre[row + 1024 + c];
    }
  }
  const us* ap = phiz + (size_t)(m0 + srow) * Hn + scb;
  const us* wr = rWih + (size_t)(c0 + srow) * 1536 + 512 + scb;
  const us* wz = wr + (size_t)512 * 1536;
  const us* wn = wz + (size_t)512 * 1536;
  uint4 av = *(const uint4*)ap;
  uint4 rv = *(const uint4*)wr;
  uint4 zv = *(const uint4*)wz;
  uint4 nv = *(const uint4*)wn;
  for (int k0 = 0; k0 < Hn; k0 += 32) {
    __syncthreads();
    *(uint4*)&Asm[srow * 40 + scb] = av;
    *(uint4*)&Rs[srow * 40 + scb] = rv;
    *(uint4*)&Zs[srow * 40 + scb] = zv;
    *(uint4*)&Ns[srow * 40 + scb] = nv;
    __syncthreads();
    if (k0 + 32 < Hn) {
      av = *(const uint4*)(ap + k0 + 32);
      rv = *(const uint4*)(wr + k0 + 32);
      zv = *(const uint4*)(wz + k0 + 32);
      nv = *(const uint4*)(wn + k0 + 32);
    }
    bf16x8 a = *(const bf16x8*)&Asm[(w * 16 + l15) * 40 + q * 8];
    #pragma unroll
    for (int j = 0; j < 4; ++j) {
      bf16x8 br = *(const bf16x8*)&Rs[(j * 16 + l15) * 40 + q * 8];
      bf16x8 bz = *(const bf16x8*)&Zs[(j * 16 + l15) * 40 + q * 8];
      bf16x8 bn = *(const bf16x8*)&Ns[(j * 16 + l15) * 40 + q * 8];
      aR[j] = __builtin_amdgcn_mfma_f32_16x16x32_bf16(a, br, aR[j], 0, 0, 0);
      aZ[j] = __builtin_amdgcn_mfma_f32_16x16x32_bf16(a, bz, aZ[j], 0, 0, 0);
      aI[j] = __builtin_amdgcn_mfma_f32_16x16x32_bf16(a, bn, aI[j], 0, 0, 0);
    }
  }
  #pragma unroll
  for (int j = 0; j < 4; ++j) {
    const int c = c0 + j * 16 + l15;
    const float bR = bih[c] + bhh[c];
    const float bZ = bih[Hn + c] + bhh[Hn + c];
    const float bI = bih[2 * Hn + c];
    const float bH = bhh[2 * Hn + c];
    #pragma unroll
    for (int r = 0; r < 4; ++r) {
      const int m = m0 + w * 16 + q * 4 + r;
      const float h = b2f(hprev[(size_t)m * Hn + c]);
      const float rg = sigmf(aR[j][r] + bR);
      const float zg = sigmf(aZ[j][r] + bZ);
      const float ng = tanhf(aI[j][r] + bI + rg * (aH[j][r] + bH));
      hnew[(size_t)m * Hn + c] = f2b((1.0f - zg) * ng + zg * h);
    }
  }
}

// decoder GEMM tile + fused BCE reduction. smem >= 10256 B.
__device__ void tile_nll(
    int bx, int by, const us* dec, const us* dmW, const float* dmb,
    const float* xt, float* nll, char* smemc)
{
  us* As = (us*)smemc; us* Bs = (us*)(smemc + 5120);
  float* red = (float*)(smemc + 10240);
  const int tid = threadIdx.x, srow = tid >> 2, scb = (tid & 3) * 8;
  const int lane = tid & 63, w = tid >> 6, l15 = lane & 15, q = lane >> 4;
  const int m0 = by * 64, n0 = bx * 64;
  f32x4 acc[4];
  #pragma unroll
  for (int j = 0; j < 4; ++j) acc[j] = (f32x4){0.f, 0.f, 0.f, 0.f};
  const int wrow = (n0 + srow < Xn) ? (n0 + srow) : (Xn - 1);
  const us* ap = dec + (size_t)(m0 + srow) * Hn + scb;
  const us* wp = dmW + (size_t)wrow * Hn + scb;
  uint4 av = *(const uint4*)ap;
  uint4 wv = *(const uint4*)wp;
  for (int k0 = 0; k0 < Hn; k0 += 32) {
    __syncthreads();
    *(uint4*)&As[srow * 40 + scb] = av;
    *(uint4*)&Bs[srow * 40 + scb] = wv;
    __syncthreads();
    if (k0 + 32 < Hn) {
      av = *(const uint4*)(ap + k0 + 32);
      wv = *(const uint4*)(wp + k0 + 32);
    }
    bf16x8 a = *(const bf16x8*)&As[(w * 16 + l15) * 40 + q * 8];
    #pragma unroll
    for (int j = 0; j < 4; ++j) {
      bf16x8 b = *(const bf16x8*)&Bs[(j * 16 + l15) * 40 + q * 8];
      acc[j] = __builtin_amdgcn_mfma_f32_16x16x32_bf16(a, b, acc[j], 0, 0, 0);
    }
  }
  float sum = 0.0f;
  #pragma unroll
  for (int j = 0; j < 4; ++j) {
    const int n = n0 + j * 16 + l15;
    if (n < Xn) {
      const float bv = dmb[n];
      #pragma unroll
      for (int r = 0; r < 4; ++r) {
        const int m = m0 + w * 16 + q * 4 + r;
        const float a = acc[j][r] + bv;
        const float xv = xt[(size_t)m * Xn + n];
        sum += splusf(-a) + (1.0f - xv) * a;
      }
    }
  }
  const float s = block_sum(sum, red);
  if (tid == 0) atomicAdd(nll, s);
}

// dual-head stats tile (MODE 0: prior stats fp32; MODE 1: f sample + f_kld). smem >= 15376 B.
template <int MODE>
__device__ void stat_dual(int vb,
    const us* Ain, const us* Wm, const float* bm, const us* Ws, const float* bs,
    const float* eps, us* o0b, float* o_pm, float* o_ps, float* kacc, char* smemc)
{
  us* As = (us*)smemc; us* Ms = (us*)(smemc + 5120); us* Ss = (us*)(smemc + 10240);
  float* red = (float*)(smemc + 15360);
  const int tid = threadIdx.x, srow = tid >> 2, scb = (tid & 3) * 8;
  const int lane = tid & 63, w = tid >> 6, l15 = lane & 15, q = lane >> 4;
  const int m0 = vb * 64;
  f32x4 am[4], as_[4];
  #pragma unroll
  for (int j = 0; j < 4; ++j) { am[j] = (f32x4){0.f, 0.f, 0.f, 0.f}; as_[j] = am[j]; }
  const us* ap = Ain + (size_t)(m0 + srow) * Hn + scb;
  const us* mp = Wm + (size_t)srow * Hn + scb;
  const us* sp = Ws + (size_t)srow * Hn + scb;
  uint4 av = *(const uint4*)ap;
  uint4 mv = *(const uint4*)mp;
  uint4 sv = *(const uint4*)sp;
  for (int k0 = 0; k0 < Hn; k0 += 32) {
    __syncthreads();
    *(uint4*)&As[srow * 40 + scb] = av;
    *(uint4*)&Ms[srow * 40 + scb] = mv;
    *(uint4*)&Ss[srow * 40 + scb] = sv;
    __syncthreads();
    if (k0 + 32 < Hn) {
      av = *(const uint4*)(ap + k0 + 32);
      mv = *(const uint4*)(mp + k0 + 32);
      sv = *(const uint4*)(sp + k0 + 32);
    }
    bf16x8 a = *(const bf16x8*)&As[(w * 16 + l15) * 40 + q * 8];
    #pragma unroll
    for (int j = 0; j < 4; ++j) {
      bf16x8 b0 = *(const bf16x8*)&Ms[(j * 16 + l15) * 40 + q * 8];
      bf16x8 b1 = *(const bf16x8*)&Ss[(j * 16 + l15) * 40 + q * 8];
      am[j]  = __builtin_amdgcn_mfma_f32_16x16x32_bf16(a, b0, am[j], 0, 0, 0);
      as_[j] = __builtin_amdgcn_mfma_f32_16x16x32_bf16(a, b1, as_[j], 0, 0, 0);
    }
  }
  float kld = 0.0f;
  #pragma unroll
  for (int j = 0; j < 4; ++j) {
    const int c = j * 16 + l15;
    const float bmv = bm[c], bsv = bs[c];
    #pragma unroll
    for (int r = 0; r < 4; ++r) {
      const int m = m0 + w * 16 + q * 4 + r;
      const float mu = am[j][r] + bmv;
      const float sd = splusf(as_[j][r] + bsv);
      if (MODE == 0) {
        o_pm[(size_t)m * Zn + c] = mu;
        o_ps[(size_t)m * Zn + c] = sd;
      } else {
        o0b[(size_t)m * Zn + c] = f2b(eps[(size_t)m * Zn + c] * sd + mu);
        kld += mu * mu + sd * sd - 2.0f * __logf(sd) - 1.0f;
      }
    }
  }
  if (MODE != 0) {
    const float s = block_sum(kld, red);
    if (tid == 0) atomicAdd(kacc, 0.5f * s);
  }
}

// enc stats + z_kld + fused K=64 phiz GEMM (zt kept in LDS). smem >= 24592 B.
__device__ void statphiz(int vb,
    const us* ze, const us* Wm, const float* bm, const us* Ws, const float* bs,
    const float* eps, const float* zpm, const float* zps,
    const us* pzW, const float* pzb, us* phiz, float* kacc, char* smemc)
{
  us* As = (us*)smemc; us* Ms = (us*)(smemc + 5120); us* Ss = (us*)(smemc + 10240);
  us* ztL = (us*)(smemc + 15360);       // [64][72] = 9216 B
  float* red = (float*)(smemc + 24576);
  const int tid = threadIdx.x, srow = tid >> 2, scb = (tid & 3) * 8;
  const int lane = tid & 63, w = tid >> 6, l15 = lane & 15, q = lane >> 4;
  const int m0 = vb * 64;
  f32x4 am[4], as_[4];
  #pragma unroll
  for (int j = 0; j < 4; ++j) { am[j] = (f32x4){0.f, 0.f, 0.f, 0.f}; as_[j] = am[j]; }
  const us* ap = ze + (size_t)(m0 + srow) * Hn + scb;
  const us* mp = Wm + (size_t)srow * Hn + scb;
  const us* sp = Ws + (size_t)srow * Hn + scb;
  uint4 av = *(const uint4*)ap;
  uint4 mv = *(const uint4*)mp;
  uint4 sv = *(const uint4*)sp;
  for (int k0 = 0; k0 < Hn; k0 += 32) {
    __syncthreads();
    *(uint4*)&As[srow * 40 + scb] = av;
    *(uint4*)&Ms[srow * 40 + scb] = mv;
    *(uint4*)&Ss[srow * 40 + scb] = sv;
    __syncthreads();
    if (k0 + 32 < Hn) {
      av = *(const uint4*)(ap + k0 + 32);
      mv = *(const uint4*)(mp + k0 + 32);
      sv = *(const uint4*)(sp + k0 + 32);
    }
    bf16x8 a = *(const bf16x8*)&As[(w * 16 + l15) * 40 + q * 8];
    #pragma unroll
    for (int j = 0; j < 4; ++j) {
      bf16x8 b0 = *(const bf16x8*)&Ms[(j * 16 + l15) * 40 + q * 8];
      bf16x8 b1 = *(const bf16x8*)&Ss[(j * 16 + l15) * 40 + q * 8];
      am[j]  = __builtin_amdgcn_mfma_f32_16x16x32_bf16(a, b0, am[j], 0, 0, 0);
      as_[j] = __builtin_amdgcn_mfma_f32_16x16x32_bf16(a, b1, as_[j], 0, 0, 0);
    }
  }
  float kld = 0.0f;
  #pragma unroll
  for (int j = 0; j < 4; ++j) {
    const int c = j * 16 + l15;
    const float bmv = bm[c], bsv = bs[c];
    #pragma unroll
    for (int r = 0; r < 4; ++r) {
      const int row = w * 16 + q * 4 + r;
      const int m = m0 + row;
      const float mu = am[j][r] + bmv;
      const float sd = splusf(as_[j][r] + bsv);
      ztL[row * 72 + c] = f2b(eps[(size_t)m * Zn + c] * sd + mu);
      const float pm = zpm[(size_t)m * Zn + c];
      const float ps = zps[(size_t)m * Zn + c];
      const float dd = (mu - pm) / ps;
      const float rr = sd / ps;
      kld += dd * dd + rr * rr - 2.0f * __logf(rr) - 1.0f;
    }
  }
  const float s = block_sum(kld, red);   // has __syncthreads -> ztL visible to all
  if (tid == 0) atomicAdd(kacc, 0.5f * s);
  // phiz = relu(ztL @ pzW^T + pzb), K=64, 8 column chunks
  for (int cc = 0; cc < 8; ++cc) {
    f32x4 acc[4];
    #pragma unroll
    for (int j = 0; j < 4; ++j) acc[j] = (f32x4){0.f, 0.f, 0.f, 0.f};
    #pragma unroll
    for (int k0 = 0; k0 < 64; k0 += 32) {
      uint4 wv = *(const uint4*)(pzW + (size_t)(cc * 64 + srow) * 64 + k0 + scb);
      __syncthreads();
      *(uint4*)&As[srow * 40 + scb] = wv;
      __syncthreads();
      bf16x8 a = *(const bf16x8*)&ztL[(w * 16 + l15) * 72 + k0 + q * 8];
      #pragma unroll
      for (int j = 0; j < 4; ++j) {
        bf16x8 b = *(const bf16x8*)&As[(j * 16 + l15) * 40 + q * 8];
        acc[j] = __builtin_amdgcn_mfma_f32_16x16x32_bf16(a, b, acc[j], 0, 0, 0);
      }
    }
    #pragma unroll
    for (int j = 0; j < 4; ++j) {
      const int col = cc * 64 + j * 16 + l15;
      const float bz = pzb[col];
      #pragma unroll
      for (int r = 0; r < 4; ++r) {
        const int row = w * 16 + q * 4 + r;
        phiz[(size_t)(m0 + row) * Hn + col] = f2b(fmaxf(acc[j][r] + bz, 0.f));
      }
    }
  }
}

// ================= global kernels =================
__global__ __launch_bounds__(256) void g_A1(
    const float* X, const us* W, const float* bias, us* C)
{
  __shared__ alignas(16) char sm[10240];
  tile_gA1(blockIdx.x, blockIdx.y, X, W, bias, C, sm);
}

__global__ __launch_bounds__(256) void g_gemm(
    const us* A, const us* W, int ldw, int K, const float* bias, us* C, int ldc)
{
  __shared__ alignas(16) char sm[10240];
  tile_gemmx<1, true, false, 0, true>(blockIdx.x, blockIdx.y, A, W, ldw, K,
      nullptr, nullptr, 0, 0, nullptr, nullptr, 0, bias, C, ldc, sm);
}

// bulk zeprePX = phi_x(all t) @ zeW1[:, :512]^T  (no bias, no relu, bf16 out)
__global__ __launch_bounds__(256) void g_bulkZE(
    const us* A, const us* zeW1, us* out)
{
  __shared__ alignas(16) char sm[10240];
  tile_gemmx<1, false, false, 0, false>(blockIdx.x, blockIdx.y, A, zeW1, 1024, Hn,
      nullptr, nullptr, 0, 0, nullptr, nullptr, 0, nullptr, out, Hn, sm);
}

__global__ __launch_bounds__(256) void g_gruB(
    const us* A0, const us* Wih, const us* hprev, const us* Whh,
    const float* bih, const float* bhh, us* hnew)
{
  __shared__ alignas(16) char sm[20480];
  tile_gru_fe(blockIdx.x, blockIdx.y, A0, Wih, hprev, Whh, bih, bhh, hnew, sm);
}

__global__ __launch_bounds__(256) void g_statf(
    const us* fh, const us* femW, const float* femb, const us* fesW, const float* fesb,
    const float* eps_f, us* fbuf, float* kacc)
{
  __shared__ alignas(16) char sm[15376];
  stat_dual<1>(blockIdx.x, fh, femW, femb, fesW, fesb, eps_f,
               fbuf, nullptr, nullptr, kacc, sm);
}

// P23: Cpre_gru(192) | Cpre_dec(64) | zp0(64) | zepre0(64, h0=0 + zeprePX[0])
__global__ __launch_bounds__(256) void g_P23(
    const us* phi_f, const us* rWih, const us* dW1, const float* db1,
    float* Cpre_gru, float* Cpre_dec,
    const us* h0, const us* zpW, const float* zpb, us* zp,
    const us* zeprePX0, const us* zeW1, const float* zeb1, us* zepre)
{
  __shared__ alignas(16) char sm[10240];
  const int b = blockIdx.x;
  if (b < 192)
    tile_gemmx<1, false, true, 0, false>(b % 24, b / 24, phi_f, rWih + 1024, 1536, Hn,
        nullptr, nullptr, 0, 0, nullptr, nullptr, 0, nullptr, Cpre_gru, 1536, sm);
  else if (b < 256)
    tile_gemmx<1, false, true, 0, true>((b - 192) & 7, (b - 192) >> 3,
        phi_f, dW1 + 512, 1536, Hn, nullptr, nullptr, 0, 0,
        nullptr, nullptr, 0, db1, Cpre_dec, 512, sm);
  else if (b < 320)
    tile_gemmx<1, true, false, 0, true>((b - 256) & 7, (b - 256) >> 3, h0, zpW, Hn, Hn,
        nullptr, nullptr, 0, 0, nullptr, nullptr, 0, zpb, zp, Hn, sm);
  else
    tile_gemmx<1, true, false, 2, true>((b - 320) & 7, (b - 320) >> 3,
        h0, zeW1 + 512, 1024, Hn, nullptr, nullptr, 0, 0,
        nullptr, zeprePX0, 512, zeb1, zepre, Hn, sm);
}

// P4: ze0(64) | zpstat0(8)
__global__ __launch_bounds__(256) void g_P4(
    const us* zepre, const us* zeW2, const float* zeb2, us* ze,
    const us* zp, const us* zpmW, const float* zpmb, const us* zpsW, const float* zpsb,
    float* zpm, float* zps)
{
  __shared__ alignas(16) char sm[15376];
  const int b = blockIdx.x;
  if (b < 64)
    tile_gemmx<1, true, false, 0, true>(b & 7, b >> 3, zepre, zeW2, Hn, Hn,
        nullptr, nullptr, 0, 0, nullptr, nullptr, 0, zeb2, ze, Hn, sm);
  else
    stat_dual<0>(b - 64, zp, zpmW, zpmb, zpsW, zpsb,
                 nullptr, nullptr, zpm, zps, nullptr, sm);
}

// Stage A: statphiz(8) | gipre(192)
__global__ __launch_bounds__(256) void g_A(
    const us* ze, const us* zemW, const float* zemb, const us* zesW, const float* zesb,
    const float* eps_zt, const float* zpm, const float* zps,
    const us* pzW, const float* pzb, us* phiz, float* kacc,
    const us* px_t, const us* rWih, const float* Cpre_gru, float* gipre)
{
  __shared__ alignas(16) char sm[24832];
  const int b = blockIdx.x;
  if (b < 8)
    statphiz(b, ze, zemW, zemb, zesW, zesb, eps_zt, zpm, zps,
             pzW, pzb, phiz, kacc, sm);
  else {
    const int tb = b - 8;
    tile_gemmx<1, false, true, 1, false>(tb % 24, tb / 24, px_t, rWih, 1536, Hn,
        nullptr, nullptr, 0, 0, Cpre_gru, nullptr, 1536, nullptr, gipre, 1536, sm);
  }
}

// Stage B: gru_fin(64) | dtmp(64)
__global__ __launch_bounds__(256) void g_B(
    const us* phiz, const us* rWih, const float* gipre, const float* ghpre,
    const us* hprev, const float* rbih, const float* rbhh, us* hnew,
    const us* dW1, const float* dtmph, us* dtmp)
{
  __shared__ alignas(16) char sm[20480];
  const int b = blockIdx.x;
  if (b < 64)
    tile_gru_fin(b & 7, b >> 3, phiz, rWih, gipre, ghpre, hprev, rbih, rbhh, hnew, sm);
  else
    tile_gemmx<1, true, false, 1, false>((b - 64) & 7, (b - 64) >> 3, phiz, dW1, 1536, Hn,
        nullptr, nullptr, 0, 0, dtmph, nullptr, 512, nullptr, dtmp, Hn, sm);
}

// Stage C: dec(64) | zp'(64) | zepre'(64, K=512 + zeprePX init) | dtmph'(64)
__global__ __launch_bounds__(256) void g_C(
    const us* dtmp, const us* dW2, const float* db2, us* dec,
    const us* hnext, const us* zpW, const float* zpb, us* zp,
    const us* zeprePX1, const us* zeW1, const float* zeb1, us* zepre,
    const us* dW1, const float* Cpre_dec, float* dtmph)
{
  __shared__ alignas(16) char sm[10240];
  const int b = blockIdx.x;
  if (b < 64)
    tile_gemmx<1, true, false, 0, true>(b & 7, b >> 3, dtmp, dW2, Hn, Hn,
        nullptr, nullptr, 0, 0, nullptr, nullptr, 0, db2, dec, Hn, sm);
  else if (b < 128)
    tile_gemmx<1, true, false, 0, true>((b - 64) & 7, (b - 64) >> 3, hnext, zpW, Hn, Hn,
        nullptr, nullptr, 0, 0, nullptr, nullptr, 0, zpb, zp, Hn, sm);
  else if (b < 192)
    tile_gemmx<1, true, false, 2, true>((b - 128) & 7, (b - 128) >> 3,
        hnext, zeW1 + 512, 1024, Hn, nullptr, nullptr, 0, 0,
        nullptr, zeprePX1, 512, zeb1, zepre, Hn, sm);
  else
    tile_gemmx<1, false, true, 1, false>((b - 192) & 7, (b - 192) >> 3,
        hnext, dW1 + 1024, 1536, Hn, nullptr, nullptr, 0, 0,
        Cpre_dec, nullptr, 512, nullptr, dtmph, 512, sm);
}

// Stage D: nll(104) | ze'(64) | zpstat'(8) | ghpre'(192)
__global__ __launch_bounds__(256) void g_D(
    const us* dec, const us* dmW, const float* dmb, const float* xt, float* nll,
    const us* zepre, const us* zeW2, const float* zeb2, us* ze,
    const us* zp, const us* zpmW, const float* zpmb, const us* zpsW, const float* zpsb,
    float* zpm, float* zps,
    const us* hnext, const us* rWhh, float* ghpre)
{
  __shared__ alignas(16) char sm[15376];
  const int b = blockIdx.x;
  if (b < 104)
    tile_nll(b % 13, b / 13, dec, dmW, dmb, xt, nll, sm);
  else if (b < 168)
    tile_gemmx<1, true, false, 0, true>((b - 104) & 7, (b - 104) >> 3, zepre, zeW2, Hn, Hn,
        nullptr, nullptr, 0, 0, nullptr, nullptr, 0, zeb2, ze, Hn, sm);
  else if (b < 176)
    stat_dual<0>(b - 168, zp, zpmW, zpmb, zpsW, zpsb,
                 nullptr, nullptr, zpm, zps, nullptr, sm);
  else {
    const int tb = b - 176;
    tile_gemmx<1, false, true, 0, false>(tb % 24, tb / 24, hnext, rWhh, Hn, Hn,
        nullptr, nullptr, 0, 0, nullptr, nullptr, 0, nullptr, ghpre, 1536, sm);
  }
}

} // anonymous namespace

extern "C" void kernel_launch(void* const* d_in, const int* in_sizes, int n_in,
                              void* d_out, int out_size, void* d_ws, size_t ws_size,
                              hipStream_t stream)
{
  (void)in_sizes; (void)n_in; (void)out_size; (void)ws_size;
  const float* x     = (const float*)d_in[0];
  const float* eps_f = (const float*)d_in[1];
  const float* eps_z = (const float*)d_in[2];
  const float* pxW1  = (const float*)d_in[3];
  const float* pxb1  = (const float*)d_in[4];
  const float* pxW2  = (const float*)d_in[5];
  const float* pxb2  = (const float*)d_in[6];
  const float* pzW   = (const float*)d_in[7];
  const float* pzb   = (const float*)d_in[8];
  const float* pfW   = (const float*)d_in[9];
  const float* pfb   = (const float*)d_in[10];
  const float* rWih  = (const float*)d_in[11];
  const float* rWhh  = (const float*)d_in[12];
  const float* rbih  = (const float*)d_in[13];
  const float* rbhh  = (const float*)d_in[14];
  const float* zpW   = (const float*)d_in[15];
  const float* zpb   = (const float*)d_in[16];
  const float* zpmW  = (const float*)d_in[17];
  const float* zpmb  = (const float*)d_in[18];
  const float* zpsW  = (const float*)d_in[19];
  const float* zpsb  = (const float*)d_in[20];
  const float* feWih = (const float*)d_in[21];
  const float* feWhh = (const float*)d_in[22];
  const float* febih = (const float*)d_in[23];
  const float* febhh = (const float*)d_in[24];
  const float* femW  = (const float*)d_in[25];
  const float* femb  = (const float*)d_in[26];
  const float* fesW  = (const float*)d_in[27];
  const float* fesb  = (const float*)d_in[28];
  const float* zeW1  = (const float*)d_in[29];
  const float* zeb1  = (const float*)d_in[30];
  const float* zeW2  = (const float*)d_in[31];
  const float* zeb2  = (const float*)d_in[32];
  const float* zemW  = (const float*)d_in[33];
  const float* zemb  = (const float*)d_in[34];
  const float* zesW  = (const float*)d_in[35];
  const float* zesb  = (const float*)d_in[36];
  const float* dW1   = (const float*)d_in[37];
  const float* db1   = (const float*)d_in[38];
  const float* dW2   = (const float*)d_in[39];
  const float* db2   = (const float*)d_in[40];
  const float* dmW   = (const float*)d_in[41];
  const float* dmb   = (const float*)d_in[42];
  float* out = (float*)d_out;

  char* base = (char*)d_ws;
  size_t off = 0;
  auto ab = [&](size_t bytes) -> void* {
    void* p = base + off;
    off += (bytes + 255) & ~(size_t)255;
    return p;
  };

  // bf16 weights
  us* b_pxW1  = (us*)ab((size_t)512 * XnP * 2);
  us* b_pxW2  = (us*)ab((size_t)512 * 512 * 2);
  us* b_pzW   = (us*)ab((size_t)512 * 64 * 2);
  us* b_pfW   = (us*)ab((size_t)512 * 64 * 2);
  us* b_rWih  = (us*)ab((size_t)1536 * 1536 * 2);
  us* b_rWhh  = (us*)ab((size_t)1536 * 512 * 2);
  us* b_zpW   = (us*)ab((size_t)512 * 512 * 2);
  us* b_zpmW  = (us*)ab((size_t)64 * 512 * 2);
  us* b_zpsW  = (us*)ab((size_t)64 * 512 * 2);
  us* b_feWih = (us*)ab((size_t)1536 * 512 * 2);
  us* b_feWhh = (us*)ab((size_t)1536 * 512 * 2);
  us* b_femW  = (us*)ab((size_t)64 * 512 * 2);
  us* b_fesW  = (us*)ab((size_t)64 * 512 * 2);
  us* b_zeW1  = (us*)ab((size_t)512 * 1024 * 2);
  us* b_zeW2  = (us*)ab((size_t)512 * 512 * 2);
  us* b_zemW  = (us*)ab((size_t)64 * 512 * 2);
  us* b_zesW  = (us*)ab((size_t)64 * 512 * 2);
  us* b_dW1   = (us*)ab((size_t)512 * 1536 * 2);
  us* b_dW2   = (us*)ab((size_t)512 * 512 * 2);
  us* b_dmW   = (us*)ab((size_t)Xn * 512 * 2);

  // activations
  us* phi_x   = (us*)ab((size_t)Tn * Bn * Hn * 2);
  us* tmpA    = (us*)ab((size_t)Tn * Bn * Hn * 2);
  us* zeprePX = (us*)ab((size_t)Tn * Bn * Hn * 2);
  us* fh_a  = (us*)ab((size_t)Bn * Hn * 2);
  us* h_a   = (us*)ab((size_t)Bn * Hn * 2);   // adjacent to fh_a (one memset)
  us* fh_b  = (us*)ab((size_t)Bn * Hn * 2);
  us* h_b   = (us*)ab((size_t)Bn * Hn * 2);
  us* fbuf  = (us*)ab((size_t)Bn * Fn * 2);
  us* phi_f = (us*)ab((size_t)Bn * Hn * 2);
  us* zp    = (us*)ab((size_t)Bn * Hn * 2);
  us* zepre = (us*)ab((size_t)Bn * Hn * 2);
  us* ze    = (us*)ab((size_t)Bn * Hn * 2);
  us* phiz  = (us*)ab((size_t)Bn * Hn * 2);
  us* dtmp  = (us*)ab((size_t)Bn * Hn * 2);
  us* dec   = (us*)ab((size_t)Bn * Hn * 2);
  float* zpm = (float*)ab((size_t)Bn * Zn * 4);
  float* zps = (float*)ab((size_t)Bn * Zn * 4);
  float* Cpre_gru = (float*)ab((size_t)Bn * 1536 * 4);
  float* Cpre_dec = (float*)ab((size_t)Bn * 512 * 4);
  float* gipre    = (float*)ab((size_t)Bn * 1536 * 4);
  float* ghpre    = (float*)ab((size_t)Bn * 1536 * 4);
  float* dtmph    = (float*)ab((size_t)Bn * 512 * 4);

  hipMemsetAsync(d_out, 0, 3 * sizeof(float), stream);
  hipMemsetAsync(fh_a, 0, 2 * (size_t)Bn * Hn * 2, stream);    // fh_a + h_a
  hipMemsetAsync(ghpre, 0, (size_t)Bn * 1536 * 4, stream);     // gh(h0=0)=0

  const dim3 blk(256);
  auto CVT = [&](const float* s, us* d, size_t n) {
    cvt<<<dim3((unsigned)((n + 255) / 256)), blk, 0, stream>>>(s, d, (int)n);
  };

  {
    const size_t n = (size_t)512 * XnP;
    cvt_pad<<<dim3((unsigned)((n + 255) / 256)), blk, 0, stream>>>(pxW1, b_pxW1, Xn, XnP, (int)n);
  }
  CVT(pxW2, b_pxW2, (size_t)512 * 512);
  CVT(pzW, b_pzW, (size_t)512 * 64);
  CVT(pfW, b_pfW, (size_t)512 * 64);
  CVT(rWih, b_rWih, (size_t)1536 * 1536);
  CVT(rWhh, b_rWhh, (size_t)1536 * 512);
  CVT(zpW, b_zpW, (size_t)512 * 512);
  CVT(zpmW, b_zpmW, (size_t)64 * 512);
  CVT(zpsW, b_zpsW, (size_t)64 * 512);
  CVT(feWih, b_feWih, (size_t)1536 * 512);
  CVT(feWhh, b_feWhh, (size_t)1536 * 512);
  CVT(femW, b_femW, (size_t)64 * 512);
  CVT(fesW, b_fesW, (size_t)64 * 512);
  CVT(zeW1, b_zeW1, (size_t)512 * 1024);
  CVT(zeW2, b_zeW2, (size_t)512 * 512);
  CVT(zemW, b_zemW, (size_t)64 * 512);
  CVT(zesW, b_zesW, (size_t)64 * 512);
  CVT(dW1, b_dW1, (size_t)512 * 1536);
  CVT(dW2, b_dW2, (size_t)512 * 512);
  CVT(dmW, b_dmW, (size_t)Xn * 512);

  // ---- Phase A: phi_x for all T (direct fp32 x read), then bulk zeprePX ----
  g_A1<<<dim3(8, Tn * Bn / 64), blk, 0, stream>>>(x, b_pxW1, pxb1, tmpA);
  g_gemm<<<dim3(8, Tn * Bn / 64), blk, 0, stream>>>(tmpA, b_pxW2, Hn, Hn, pxb2, phi_x, Hn);
  g_bulkZE<<<dim3(8, Tn * Bn / 64), blk, 0, stream>>>(phi_x, b_zeW1, zeprePX);

  // ---- Phase B: f-encoder GRU ----
  us* fc = fh_a; us* fn2 = fh_b;
  for (int t = 0; t < Tn; ++t) {
    g_gruB<<<dim3(8, 8), blk, 0, stream>>>(
        phi_x + (size_t)t * Bn * Hn, b_feWih, fc, b_feWhh, febih, febhh, fn2);
    us* sw = fc; fc = fn2; fn2 = sw;
  }

  // ---- Phase C: f stats (Tn even -> final hidden in fh_a) ----
  g_statf<<<dim3(8), blk, 0, stream>>>(fh_a, b_femW, femb, b_fesW, fesb, eps_f, fbuf, out + 0);

  // ---- Prologue ----
  g_gemm<<<dim3(8, 8), blk, 0, stream>>>(fbuf, b_pfW, Fn, Fn, pfb, phi_f, Hn);
  g_P23<<<dim3(384), blk, 0, stream>>>(phi_f, b_rWih, b_dW1, db1, Cpre_gru, Cpre_dec,
                                       h_a, b_zpW, zpb, zp, zeprePX, b_zeW1, zeb1, zepre);
  g_P4<<<dim3(72), blk, 0, stream>>>(zepre, b_zeW2, zeb2, ze,
                                     zp, b_zpmW, zpmb, b_zpsW, zpsb, zpm, zps);

  // ---- Phase D: 4 launches per timestep ----
  for (int t = 0; t < Tn; ++t) {
    const us* hcur = (t & 1) ? h_b : h_a;
    us* hnext      = (t & 1) ? h_a : h_b;
    const bool last = (t == Tn - 1);
    const us* px_t = phi_x + (size_t)t * Bn * Hn;
    const float* dtmph_sel = (t == 0) ? Cpre_dec : dtmph;

    g_A<<<dim3(200), blk, 0, stream>>>(
        ze, b_zemW, zemb, b_zesW, zesb, eps_z + (size_t)t * Bn * Zn, zpm, zps,
        b_pzW, pzb, phiz, out + 1, px_t, b_rWih, Cpre_gru, gipre);

    g_B<<<dim3(128), blk, 0, stream>>>(
        phiz, b_rWih, gipre, ghpre, hcur, rbih, rbhh, hnext,
        b_dW1, dtmph_sel, dtmp);

    g_C<<<dim3(last ? 64 : 256), blk, 0, stream>>>(
        dtmp, b_dW2, db2, dec, hnext, b_zpW, zpb, zp,
        zeprePX + (size_t)(t + 1) * Bn * Hn, b_zeW1, zeb1, zepre,
        b_dW1, Cpre_dec, dtmph);

    g_D<<<dim3(last ? 104 : 368), blk, 0, stream>>>(
        dec, b_dmW, dmb, x + (size_t)t * Bn * Xn, out + 2,
        zepre, b_zeW2, zeb2, ze,
        zp, b_zpmW, zpmb, b_zpsW, zpsb, zpm, zps,
        hnext, b_rWhh, ghpre);
  }
}